// Round 5
// baseline (15362.065 us; speedup 1.0000x reference)
//
#include <hip/hip_runtime.h>
#include <math.h>

#define NN 716
#define NSQ (716*716)
typedef unsigned short bfu;
typedef __attribute__((ext_vector_type(8))) __bf16 bf16x8;
typedef __attribute__((ext_vector_type(4))) float f32x4;

__device__ __forceinline__ float b2f(bfu u){ union{unsigned int i; float f;} x; x.i = ((unsigned int)u)<<16; return x.f; }
__device__ __forceinline__ bfu f2b(float f){ union{float fv; unsigned int i;} x; x.fv = f; unsigned int r = (x.i + 0x7fffu + ((x.i>>16)&1u)) >> 16; return (bfu)r; }
__device__ __forceinline__ float sigmoidf_(float x){ return 1.f/(1.f+expf(-x)); }

__device__ __forceinline__ float fexp_(float x){
#if __has_builtin(__builtin_amdgcn_exp2f)
  return __builtin_amdgcn_exp2f(x * 1.44269504088896340736f);
#else
  return __expf(x);
#endif
}
__device__ __forceinline__ float frcp_(float x){
#if __has_builtin(__builtin_amdgcn_rcpf)
  return __builtin_amdgcn_rcpf(x);
#else
  return 1.f/x;
#endif
}
__device__ __forceinline__ float fsig_(float x){ return frcp_(1.f + fexp_(-x)); }
__device__ __forceinline__ float ftanh_(float x){
  float xc = fminf(fmaxf(x, -30.f), 30.f);
  float e = fexp_(-2.f*xc);
  return (1.f - e) * frcp_(1.f + e);
}

// ---------------- init / adjacency construction ----------------

__global__ void k_ind(const float* __restrict__ hist, int* __restrict__ ind){
  int b = threadIdx.x; if (b >= 64) return;
  float v = hist[((b*12+11)*NN + 0)*2 + 1];
  ind[b] = ((int)(v*288.0f)) % 288;
}

__global__ void k_dg1(const float* __restrict__ p1, const float* __restrict__ pk,
                      const int* __restrict__ ind, float* __restrict__ tmp1){
  int b = blockIdx.x;
  __shared__ float p1s[40];
  if (threadIdx.x < 40) p1s[threadIdx.x] = p1[ind[b]*40 + threadIdx.x];
  __syncthreads();
  for (int jk = threadIdx.x; jk < 1600; jk += 256){
    float acc = 0.f;
    for (int i = 0; i < 40; ++i) acc += p1s[i]*pk[i*1600 + jk];
    tmp1[b*1600 + jk] = acc;
  }
}

__global__ void k_dg2(const float* __restrict__ p2, const float* __restrict__ tmp1,
                      float* __restrict__ tmp2){
  int b = blockIdx.y;
  __shared__ float ts[1600];
  for (int i = threadIdx.x; i < 1600; i += 256) ts[i] = tmp1[b*1600+i];
  __syncthreads();
  int idx = blockIdx.x*256 + threadIdx.x;
  if (idx >= NN*40) return;
  int n = idx/40, k = idx%40;
  float acc = 0.f;
  for (int j = 0; j < 40; ++j) acc += p2[n*40+j]*ts[j*40+k];
  tmp2[(long)b*NN*40 + idx] = acc;
}

__global__ void k_p3t(const float* __restrict__ p3, float* __restrict__ p3t){
  int v = blockIdx.x*256 + threadIdx.x; if (v >= NN) return;
  for (int k = 0; k < 40; ++k) p3t[k*NN + v] = p3[v*40 + k];
}

// 8 adjacency rows per block: logits (f32) -> relu -> softmax -> bf16
__global__ __launch_bounds__(256) void k_adjrow8(const float* __restrict__ p3t,
    const float* __restrict__ tmp2, bfu* __restrict__ adjb)
{
  int b = blockIdx.y, w0 = blockIdx.x*8, tid = threadIdx.x;
  int wave = tid >> 6;
  __shared__ float t2s[8][40];
  __shared__ float buf[8][720];
  __shared__ float wred[8][4];
  __shared__ float rstat[8];
  for (int i = tid; i < 320; i += 256){
    int r = i/40, k = i%40; int w = w0 + r;
    t2s[r][k] = (w < NN) ? tmp2[((long)b*NN + w)*40 + k] : 0.f;
  }
  __syncthreads();
  float lmax[8] = {0,0,0,0,0,0,0,0};
  for (int q = 0; q < 3; ++q){
    int v = tid + q*256;
    if (v < NN){
      float a[8] = {0,0,0,0,0,0,0,0};
      #pragma unroll 8
      for (int k = 0; k < 40; ++k){
        float pv = p3t[k*NN + v];
        #pragma unroll
        for (int r = 0; r < 8; ++r) a[r] += t2s[r][k]*pv;
      }
      #pragma unroll
      for (int r = 0; r < 8; ++r){
        float val = fmaxf(a[r], 0.f);
        buf[r][v] = val;
        lmax[r] = fmaxf(lmax[r], val);
      }
    }
  }
  #pragma unroll
  for (int r = 0; r < 8; ++r){
    float m = lmax[r];
    for (int s = 32; s > 0; s >>= 1) m = fmaxf(m, __shfl_xor(m, s, 64));
    if ((tid & 63) == 0) wred[r][wave] = m;
  }
  __syncthreads();
  if (tid < 8) rstat[tid] = fmaxf(fmaxf(wred[tid][0], wred[tid][1]), fmaxf(wred[tid][2], wred[tid][3]));
  __syncthreads();
  float lsum[8] = {0,0,0,0,0,0,0,0};
  for (int q = 0; q < 3; ++q){
    int v = tid + q*256;
    if (v < NN){
      #pragma unroll
      for (int r = 0; r < 8; ++r){
        float e = fexp_(buf[r][v] - rstat[r]);
        buf[r][v] = e;
        lsum[r] += e;
      }
    }
  }
  __syncthreads();
  #pragma unroll
  for (int r = 0; r < 8; ++r){
    float s = lsum[r];
    for (int k = 32; k > 0; k >>= 1) s += __shfl_xor(s, k, 64);
    if ((tid & 63) == 0) wred[r][wave] = s;
  }
  __syncthreads();
  if (tid < 8) rstat[tid] = frcp_(wred[tid][0] + wred[tid][1] + wred[tid][2] + wred[tid][3]);
  __syncthreads();
  for (int q = 0; q < 3; ++q){
    int v = tid + q*256;
    if (v < NN){
      #pragma unroll
      for (int r = 0; r < 8; ++r){
        int w = w0 + r;
        if (w < NN) adjb[(long)b*NSQ + (long)w*NN + v] = f2b(buf[r][v]*rstat[r]);
      }
    }
  }
}

// xs[n][t] = sum_b x_a[b,n,t]; y[n] = sum_t xs[n][t]
__global__ void k_xs(const float* __restrict__ hist, const float* __restrict__ saW,
                     const float* __restrict__ sab, float* __restrict__ xs, float* __restrict__ y){
  int n = blockIdx.x, b = threadIdx.x; // 64 threads
  float w = saW[0], bb = sab[0];
  float ytot = 0.f;
  for (int t = 0; t < 13; ++t){
    float inp = (t == 0) ? 0.f : hist[((b*12 + (t-1))*NN + n)*2];
    float s = inp;
    for (int off = 32; off > 0; off >>= 1) s += __shfl_down(s, off, 64);
    if (b == 0){ float val = w*s + 64.f*bb; xs[n*13+t] = val; ytot += val; }
  }
  if (b == 0) y[n] = ytot;
}

__global__ void k_adjp(const float* __restrict__ xs, const float* __restrict__ y,
                       const float* __restrict__ piv, float* __restrict__ adjp){
  int i = blockIdx.y;
  __shared__ float xi[13];
  if (threadIdx.x < 13) xi[threadIdx.x] = xs[i*13+threadIdx.x];
  __syncthreads();
  int j = blockIdx.x*256 + threadIdx.x;
  if (j >= NN) return;
  float acc = 0.f;
  #pragma unroll
  for (int t = 0; t < 12; ++t) acc += xi[t]*xs[j*13+t+1];
  adjp[(long)i*NN+j] = acc / y[j] * piv[(long)i*NN+j];
}

__global__ void k_score(const float* __restrict__ adjp, float* __restrict__ score){
  int n = blockIdx.x, tid = threadIdx.x;
  float s = 0.f;
  for (int i = tid; i < NN; i += 256) s += adjp[(long)i*NN+n] + adjp[(long)n*NN+i];
  __shared__ float red[256];
  red[tid] = s; __syncthreads();
  for (int k = 128; k > 0; k >>= 1){ if (tid < k) red[tid] += red[tid+k]; __syncthreads(); }
  if (tid == 0) score[n] = red[0];
}

// bitonic sort 1024 (desc, tie->lower index first), take top 100 -> mask
__global__ void k_topk(const float* __restrict__ score, int* __restrict__ mask){
  __shared__ float v[1024];
  __shared__ int ix[1024];
  int tid = threadIdx.x;
  for (int t = tid; t < 1024; t += 256){ v[t] = (t < NN) ? score[t] : -INFINITY; ix[t] = t; }
  __syncthreads();
  for (int k = 2; k <= 1024; k <<= 1){
    for (int j = k >> 1; j > 0; j >>= 1){
      for (int t = tid; t < 1024; t += 256){
        int l = t ^ j;
        if (l > t){
          bool up = ((t & k) == 0);
          bool g = (v[t] > v[l]) || (v[t] == v[l] && ix[t] < ix[l]);
          if (up ? !g : g){
            float tv = v[t]; v[t] = v[l]; v[l] = tv;
            int ti = ix[t]; ix[t] = ix[l]; ix[l] = ti;
          }
        }
      }
      __syncthreads();
    }
  }
  for (int t = tid; t < NN; t += 256) mask[t] = 0;
  __syncthreads();
  if (tid < 100) mask[ix[tid]] = 1;
}

// build compact pivotal structure: idx[100], rank[716], u[100], ApkT[100k][100r]
__global__ void k_pivprep(const float* __restrict__ adjp, const int* __restrict__ mask,
                          int* __restrict__ idxk, int* __restrict__ rankv,
                          float* __restrict__ uvec, float* __restrict__ ApkT){
  __shared__ int sidx[100];
  int tid = threadIdx.x;
  if (tid == 0){
    int c = 0;
    for (int i = 0; i < NN; ++i){
      if (mask[i] && c < 100){ sidx[c] = i; idxk[c] = i; rankv[i] = c; ++c; }
      else rankv[i] = -1;
    }
  }
  __syncthreads();
  if (tid < 100){
    int i = sidx[tid];
    const float* row = adjp + (long)i*NN;
    float mx = 0.f;
    for (int k = 0; k < 100; ++k) mx = fmaxf(mx, row[sidx[k]]);
    float sum = 616.f * fexp_(-mx);
    for (int k = 0; k < 100; ++k) sum += fexp_(fmaxf(row[sidx[k]], 0.f) - mx);
    float inv = 1.f/sum;
    uvec[tid] = fexp_(-mx)*inv;
    for (int k = 0; k < 100; ++k)
      ApkT[k*100 + tid] = fexp_(fmaxf(row[sidx[k]], 0.f) - mx)*inv;
  }
}

// x[b,c,t,n] = start_W[c]*inp + start_b[c]
__global__ void k_init_x(const float* __restrict__ hist, const float* __restrict__ sW,
                         const float* __restrict__ sb, bfu* __restrict__ x){
  int n = blockIdx.x*256 + threadIdx.x; if (n >= NN) return;
  int t = blockIdx.y, b = blockIdx.z;
  float inp = (t == 0) ? 0.f : hist[((b*12 + (t-1))*NN + n)*2];
  #pragma unroll
  for (int c = 0; c < 32; ++c)
    x[((long)(b*32+c)*13 + t)*NN + n] = f2b(sW[c]*inp + sb[c]);
}

// identity BN params
__global__ void k_bnid(float* __restrict__ bnp){
  int c = threadIdx.x; if (c >= 32) return;
  bnp[c*2] = 1.f; bnp[c*2+1] = 0.f;
}

// permuted e1W -> bf16: k' = off2[L] + t*8 + sc  <->  k = soff[L] + sc*Tp[L] + t
__global__ void k_e1perm(const float* __restrict__ W, bfu* __restrict__ Wb){
  int i = blockIdx.x*256 + threadIdx.x;
  if (i >= 512*416) return;
  int e = i/416, kp = i%416;
  const int off2[9] = {0,96,176,248,304,352,384,408,416};
  const int soff[8] = {320,240,168,112,64,32,8,0};
  const int tpl[8]  = {12,10,9,7,6,4,3,1};
  int L = 0;
  #pragma unroll
  for (int q = 0; q < 8; ++q) if (kp >= off2[q+1]) L = q+1;
  int r = kp - off2[L]; int t = r>>3, sc = r&7;
  int k = soff[L] + sc*tpl[L] + t;
  Wb[e*416+kp] = f2b(W[e*416+k]);
}

// ---------------- MFMA GEMM: C[m][n] = sum_k X[m][k]*A[n][k] ----------------
#define LDST 40

__global__ __launch_bounds__(256) void gemm_mfma(const bfu* __restrict__ Xg,
    const bfu* __restrict__ Ag, bfu* __restrict__ Cg,
    int M, int K, long sx, long sa, long sc,
    const float* __restrict__ bias, int relu_out, int Trow, int Tcomp)
{
  const bfu* X = Xg + (long)blockIdx.z*sx;
  const bfu* A = Ag + (long)blockIdx.z*sa;
  bfu*       C = Cg + (long)blockIdx.z*sc;
  int m0 = blockIdx.y*128, n0 = blockIdx.x*128;
  __shared__ bfu Xs[128*LDST];
  __shared__ bfu As[128*LDST];
  int tid = threadIdx.x;
  int wave = tid >> 6, lane = tid & 63;
  int wm = (wave >> 1)*64, wn = (wave & 1)*64;
  int lr = lane & 15, lg = lane >> 4;
  f32x4 acc[4][4] = {};
  int ldr = tid >> 1, ldk = (tid & 1)*16;
  int mg = m0 + ldr, ng = n0 + ldr;
  int mrow = (Trow == Tcomp) ? mg : (mg/Tcomp)*Trow + (mg%Tcomp);
  const bfu* xrow = X + (long)mrow*K;
  const bfu* arow = A + (long)ng*K;
  for (int k0 = 0; k0 < K; k0 += 32){
    int kk = k0 + ldk;
    ushort4 z4 = {0,0,0,0};
    ushort4 x0=z4,x1=z4,x2=z4,x3=z4, a0=z4,a1=z4,a2=z4,a3=z4;
    if (mg < M){
      if (kk + 16 <= K){
        const ushort4* s = (const ushort4*)(xrow + kk);
        x0=s[0]; x1=s[1]; x2=s[2]; x3=s[3];
      } else {
        bfu tv[16];
        #pragma unroll
        for (int j=0;j<16;++j) tv[j] = (kk+j < K) ? xrow[kk+j] : (bfu)0;
        const ushort4* s = (const ushort4*)tv;
        x0=s[0]; x1=s[1]; x2=s[2]; x3=s[3];
      }
    }
    if (ng < NN){
      if (kk + 16 <= K){
        const ushort4* s = (const ushort4*)(arow + kk);
        a0=s[0]; a1=s[1]; a2=s[2]; a3=s[3];
      } else {
        bfu tv[16];
        #pragma unroll
        for (int j=0;j<16;++j) tv[j] = (kk+j < K) ? arow[kk+j] : (bfu)0;
        const ushort4* s = (const ushort4*)tv;
        a0=s[0]; a1=s[1]; a2=s[2]; a3=s[3];
      }
    }
    ushort4* xd = (ushort4*)&Xs[ldr*LDST + ldk];
    xd[0]=x0; xd[1]=x1; xd[2]=x2; xd[3]=x3;
    ushort4* ad = (ushort4*)&As[ldr*LDST + ldk];
    ad[0]=a0; ad[1]=a1; ad[2]=a2; ad[3]=a3;
    __syncthreads();
    bf16x8 af[4], bfr[4];
    #pragma unroll
    for (int i=0;i<4;++i){
      af[i]  = *(const bf16x8*)&Xs[(wm + i*16 + lr)*LDST + lg*8];
      bfr[i] = *(const bf16x8*)&As[(wn + i*16 + lr)*LDST + lg*8];
    }
    #pragma unroll
    for (int i=0;i<4;++i)
      #pragma unroll
      for (int j=0;j<4;++j)
        acc[i][j] = __builtin_amdgcn_mfma_f32_16x16x32_bf16(af[i], bfr[j], acc[i][j], 0,0,0);
    __syncthreads();
  }
  #pragma unroll
  for (int i=0;i<4;++i){
    #pragma unroll
    for (int r=0;r<4;++r){
      int m = m0 + wm + i*16 + lg*4 + r;
      if (m >= M) continue;
      float bv = bias ? bias[m] : 0.f;
      #pragma unroll
      for (int j=0;j<4;++j){
        int n = n0 + wn + j*16 + lr;
        if (n < NN){
          float v = acc[i][j][r] + bv;
          if (relu_out) v = fmaxf(v, 0.f);
          C[(long)m*NN + n] = f2b(v);
        }
      }
    }
  }
}

// ---------------- pivotal diffusion via topk structure ----------------
// Y[m][i] = uniform S/716 (non-mask i) | u_r*(S-Sk) + sum_k Apk[r][k]*xk (mask i)
// optional per-channel affine (BN fold): out = sb*val + bb
__global__ __launch_bounds__(256) void k_pgdiff(const bfu* __restrict__ X,
    bfu* __restrict__ Y, const int* __restrict__ idxk, const int* __restrict__ rankv,
    const float* __restrict__ uvec, const float* __restrict__ ApkT,
    const float* __restrict__ bnp, int M, int Trow, int Tcomp)
{
  __shared__ float xks[4][100];
  int tid = threadIdx.x;
  int g = tid >> 6, lane = tid & 63;
  int m = blockIdx.x*4 + g;
  bool act = (m < M);
  float s = 0.f, sk = 0.f;
  const bfu* xr = nullptr;
  if (act){
    int mrow = (Trow == Tcomp) ? m : (m/Tcomp)*Trow + (m%Tcomp);
    xr = X + (long)mrow*NN;
    #pragma unroll
    for (int q = 0; q < 12; ++q){
      int v = lane + q*64;
      if (v < NN) s += b2f(xr[v]);
    }
    for (int o = 32; o; o >>= 1) s += __shfl_xor(s, o, 64);
    #pragma unroll
    for (int q = 0; q < 2; ++q){
      int k = lane + q*64;
      if (k < 100){
        float v = b2f(xr[idxk[k]]);
        xks[g][k] = v;
        sk += v;
      }
    }
    for (int o = 32; o; o >>= 1) sk += __shfl_xor(sk, o, 64);
  }
  __syncthreads();
  if (!act) return;
  float sb = 1.f, bb = 0.f;
  if (bnp){
    int c = (m / Tcomp) & 31;
    sb = bnp[c*2]; bb = bnp[c*2+1];
  }
  bfu* yr = Y + (long)m*NN;
  bfu uni = f2b(sb*(s*(1.f/716.f)) + bb);
  #pragma unroll
  for (int q = 0; q < 12; ++q){
    int v = lane + q*64;
    if (v < NN && rankv[v] < 0) yr[v] = uni;
  }
  #pragma unroll
  for (int q = 0; q < 2; ++q){
    int r = lane + q*64;
    if (r < 100){
      float acc = uvec[r]*(s - sk);
      for (int k = 0; k < 100; ++k) acc += ApkT[k*100 + r]*xks[g][k];
      yr[idxk[r]] = f2b(sb*acc + bb);
    }
  }
}

// ---------------- per-layer kernels ----------------

// gated temporal conv with BN-folded input: fg = tanh(filt)*sigmoid(gate)
__global__ __launch_bounds__(256) void k_fg(const bfu* __restrict__ x,
    const float* __restrict__ fW, const float* __restrict__ fb,
    const float* __restrict__ gW, const float* __restrict__ gb,
    const float* __restrict__ bnp, bfu* __restrict__ fg, int layer, int T, int Tp, int d)
{
  __shared__ float wf[2048], wg[2048], bf[32], bg[32], bnl[64];
  for (int i = threadIdx.x; i < 2048; i += 256){ wf[i] = fW[layer*2048+i]; wg[i] = gW[layer*2048+i]; }
  if (threadIdx.x < 32){ bf[threadIdx.x] = fb[layer*32+threadIdx.x]; bg[threadIdx.x] = gb[layer*32+threadIdx.x]; }
  if (threadIdx.x < 64) bnl[threadIdx.x] = bnp[threadIdx.x];
  __syncthreads();
  int n = blockIdx.x*256 + threadIdx.x; if (n >= NN) return;
  int t = blockIdx.y, b = blockIdx.z;
  float r0[32], r1[32];
  #pragma unroll
  for (int c = 0; c < 32; ++c){
    long base = ((long)(b*32+c)*T)*NN + n;
    float sc = bnl[c*2], bc = bnl[c*2+1];
    r0[c] = b2f(x[base + (long)t*NN])*sc + bc;
    r1[c] = b2f(x[base + (long)(t+d)*NN])*sc + bc;
  }
  #pragma unroll
  for (int o = 0; o < 32; ++o){
    float f = bf[o], g = bg[o];
    #pragma unroll
    for (int c = 0; c < 32; ++c){
      f += wf[(o*32+c)*2]*r0[c] + wf[(o*32+c)*2+1]*r1[c];
      g += wg[(o*32+c)*2]*r0[c] + wg[(o*32+c)*2+1]*r1[c];
    }
    fg[((long)(b*32+o)*Tp + t)*NN + n] = f2b(ftanh_(f)*fsig_(g));
  }
}

// G = (1-a)*(gb + W0*fg + W1*z1 + W2*z2), in place over F; 2 n per thread
__global__ __launch_bounds__(256) void k_xgmix2(bfu* __restrict__ F,
    const bfu* __restrict__ z1, const bfu* __restrict__ z2,
    const float* __restrict__ Wl, const float* __restrict__ bl,
    const float* __restrict__ alpha, int Tp)
{
  __shared__ float w[3072], bb[32];
  float oma = 1.f - sigmoidf_(alpha[0]);
  for (int i = threadIdx.x; i < 3072; i += 256) w[i] = oma*Wl[i];
  if (threadIdx.x < 32) bb[threadIdx.x] = oma*bl[threadIdx.x];
  __syncthreads();
  int n = (blockIdx.x*256 + threadIdx.x)*2; if (n >= NN) return;
  int t = blockIdx.y, b = blockIdx.z;
  float ax[32], ay[32];
  #pragma unroll
  for (int o = 0; o < 32; ++o){ ax[o] = bb[o]; ay[o] = bb[o]; }
  #pragma unroll
  for (int c = 0; c < 32; ++c){
    long off = ((long)(b*32+c)*Tp + t)*NN + n;
    ushort2 fv = *(const ushort2*)(F + off);
    ushort2 z1v = *(const ushort2*)(z1 + off);
    ushort2 z2v = *(const ushort2*)(z2 + off);
    float f0 = b2f(fv.x), f1 = b2f(fv.y);
    float a0 = b2f(z1v.x), a1 = b2f(z1v.y);
    float b0 = b2f(z2v.x), b1 = b2f(z2v.y);
    #pragma unroll
    for (int o = 0; o < 32; ++o){
      float w0 = w[o*96+c], w1 = w[o*96+32+c], w2 = w[o*96+64+c];
      ax[o] += w0*f0 + w1*a0 + w2*b0;
      ay[o] += w0*f1 + w1*a1 + w2*b1;
    }
  }
  #pragma unroll
  for (int o = 0; o < 32; ++o){
    long off = ((long)(b*32+o)*Tp + t)*NN + n;
    ushort2 ov; ov.x = f2b(ax[o]); ov.y = f2b(ay[o]);
    *(ushort2*)(F + off) = ov;
  }
}

// out = a_s*(pb + P0*xbn + P1*y1 + P2*y2) + G + res_bn; over F; coalesced skipP
__global__ __launch_bounds__(256) void k_combine3v(const bfu* __restrict__ x,
    bfu* __restrict__ F, const bfu* __restrict__ y1, const bfu* __restrict__ y2,
    const float* __restrict__ pWl, const float* __restrict__ pbl,
    const float* __restrict__ skWl, const float* __restrict__ skbl,
    const float* __restrict__ alpha, const float* __restrict__ bnp,
    bfu* __restrict__ skipP, int T, int Tp, int d, int off2)
{
  __shared__ float w[3072], bb[32], sw[256], sb8[8], bnl[64];
  float a_s = sigmoidf_(alpha[0]);
  for (int i = threadIdx.x; i < 3072; i += 256) w[i] = a_s*pWl[i];
  if (threadIdx.x < 32) bb[threadIdx.x] = a_s*pbl[threadIdx.x];
  sw[threadIdx.x] = skWl[threadIdx.x];
  if (threadIdx.x < 8) sb8[threadIdx.x] = skbl[threadIdx.x];
  if (threadIdx.x < 64) bnl[threadIdx.x] = bnp[threadIdx.x];
  __syncthreads();
  int n = (blockIdx.x*256 + threadIdx.x)*2; if (n >= NN) return;
  int t = blockIdx.y, b = blockIdx.z;
  float ax[32], ay[32];
  #pragma unroll
  for (int o = 0; o < 32; ++o){ ax[o] = bb[o]; ay[o] = bb[o]; }
  #pragma unroll
  for (int c = 0; c < 32; ++c){
    float sc = bnl[c*2], bc = bnl[c*2+1];
    ushort2 xv = *(const ushort2*)(x + ((long)(b*32+c)*T + t)*NN + n);
    long off = ((long)(b*32+c)*Tp + t)*NN + n;
    ushort2 y1v = *(const ushort2*)(y1 + off);
    ushort2 y2v = *(const ushort2*)(y2 + off);
    float x0 = b2f(xv.x)*sc + bc, x1 = b2f(xv.y)*sc + bc;
    float a0 = b2f(y1v.x), a1 = b2f(y1v.y);
    float b0 = b2f(y2v.x), b1 = b2f(y2v.y);
    #pragma unroll
    for (int o = 0; o < 32; ++o){
      float w0 = w[o*96+c], w1 = w[o*96+32+c], w2 = w[o*96+64+c];
      ax[o] += w0*x0 + w1*a0 + w2*b0;
      ay[o] += w0*x1 + w1*a1 + w2*b1;
    }
  }
  #pragma unroll
  for (int o = 0; o < 32; ++o){
    float sc = bnl[o*2], bc = bnl[o*2+1];
    long oidx = ((long)(b*32+o)*Tp + t)*NN + n;
    ushort2 gv = *(const ushort2*)(F + oidx);
    ushort2 rv = *(const ushort2*)(x + ((long)(b*32+o)*T + t + d)*NN + n);
    ax[o] += b2f(gv.x) + b2f(rv.x)*sc + bc;
    ay[o] += b2f(gv.y) + b2f(rv.y)*sc + bc;
    ushort2 ov; ov.x = f2b(ax[o]); ov.y = f2b(ay[o]);
    *(ushort2*)(F + oidx) = ov;
  }
  #pragma unroll
  for (int sc2 = 0; sc2 < 8; ++sc2){
    float s0 = sb8[sc2], s1 = sb8[sc2];
    #pragma unroll
    for (int c = 0; c < 32; ++c){ s0 += sw[sc2*32+c]*ax[c]; s1 += sw[sc2*32+c]*ay[c]; }
    ushort2 ov; ov.x = f2b(fmaxf(s0, 0.f)); ov.y = f2b(fmaxf(s1, 0.f));
    *(ushort2*)(skipP + ((long)b*416 + off2 + t*8 + sc2)*NN + n) = ov;
  }
}

__global__ void k_bn1(const bfu* __restrict__ x, float* __restrict__ red, int Tp){
  int c = blockIdx.y, g = blockIdx.x, tid = threadIdx.x;
  long per = (long)Tp*NN; long cnt = 64L*per;
  float s = 0.f, s2 = 0.f;
  for (long idx = (long)g*256 + tid; idx < cnt; idx += 64L*256){
    long b = idx/per, r = idx - b*per;
    float v = b2f(x[((long)b*32 + c)*per + r]);
    s += v; s2 += v*v;
  }
  __shared__ float rs[256], rs2[256];
  rs[tid] = s; rs2[tid] = s2; __syncthreads();
  for (int k = 128; k > 0; k >>= 1){
    if (tid < k){ rs[tid] += rs[tid+k]; rs2[tid] += rs2[tid+k]; }
    __syncthreads();
  }
  if (tid == 0){ red[(c*64+g)*2] = rs[0]; red[(c*64+g)*2+1] = rs2[0]; }
}

__global__ void k_bn2(const float* __restrict__ red, const float* __restrict__ gamma,
                      const float* __restrict__ beta, float* __restrict__ bnp, int layer, int Tp){
  int c = blockIdx.x;
  if (threadIdx.x != 0) return;
  float s = 0.f, s2 = 0.f;
  for (int g = 0; g < 64; ++g){ s += red[(c*64+g)*2]; s2 += red[(c*64+g)*2+1]; }
  float cnt = 64.f*Tp*716.f;
  float mu = s/cnt, var = s2/cnt - mu*mu;
  float rstd = rsqrtf(var + 1e-5f);
  float ga = gamma[layer*32+c], be = beta[layer*32+c];
  bnp[c*2] = rstd*ga; bnp[c*2+1] = be - mu*rstd*ga;
}

// ---------------- end MLP ----------------

// tiled transpose skipP[b][416][716] -> skipT[b][716][416]
__global__ __launch_bounds__(256) void k_sktr(const bfu* __restrict__ SP, bfu* __restrict__ ST){
  __shared__ bfu tile[64][66];
  int b = blockIdx.z;
  int n0 = blockIdx.x*64, k0 = blockIdx.y*64;
  int tid = threadIdx.x;
  int tr = tid >> 6, tc = tid & 63;
  #pragma unroll
  for (int p = 0; p < 16; ++p){
    int k = k0 + p*4 + tr, n = n0 + tc;
    tile[p*4+tr][tc] = (k < 416 && n < NN) ? SP[((long)b*416 + k)*NN + n] : (bfu)0;
  }
  __syncthreads();
  #pragma unroll
  for (int p = 0; p < 16; ++p){
    int n = n0 + p*4 + tr, k = k0 + tc;
    if (n < NN && k < 416) ST[((long)b*NN + n)*416 + k] = tile[tc][p*4+tr];
  }
}

__global__ __launch_bounds__(256) void k_end2(const bfu* __restrict__ H,
    const float* __restrict__ W2, const float* __restrict__ b2, float* __restrict__ out)
{
  __shared__ float w[12*512];
  for (int i = threadIdx.x; i < 6144; i += 256) w[i] = W2[i];
  __syncthreads();
  int n = blockIdx.x*256 + threadIdx.x; if (n >= NN) return;
  int b = blockIdx.y;
  float acc[12];
  #pragma unroll
  for (int o = 0; o < 12; ++o) acc[o] = b2[o];
  for (int e = 0; e < 512; ++e){
    float h = b2f(H[((long)b*512+e)*NN + n]);
    #pragma unroll
    for (int o = 0; o < 12; ++o) acc[o] += w[o*512+e]*h;
  }
  #pragma unroll
  for (int o = 0; o < 12; ++o) out[((long)b*12+o)*NN + n] = acc[o];
}

// ---------------- launch ----------------

extern "C" void kernel_launch(void* const* d_in, const int* in_sizes, int n_in,
                              void* d_out, int out_size, void* d_ws, size_t ws_size,
                              hipStream_t stream)
{
  const float* hist = (const float*)d_in[0];
  const float* alpha = (const float*)d_in[1];
  const float* p1  = (const float*)d_in[2];
  const float* p2  = (const float*)d_in[3];
  const float* p3  = (const float*)d_in[4];
  const float* pk  = (const float*)d_in[5];
  const float* piv = (const float*)d_in[6];
  const float* sW  = (const float*)d_in[7];
  const float* sb  = (const float*)d_in[8];
  const float* saW = (const float*)d_in[9];
  const float* sab = (const float*)d_in[10];
  const float* fW  = (const float*)d_in[11];
  const float* fb  = (const float*)d_in[12];
  const float* gW  = (const float*)d_in[13];
  const float* gb  = (const float*)d_in[14];
  const float* skW = (const float*)d_in[15];
  const float* skb = (const float*)d_in[16];
  const float* gcW = (const float*)d_in[17];
  const float* gcb = (const float*)d_in[18];
  const float* pgW = (const float*)d_in[19];
  const float* pgb = (const float*)d_in[20];
  const float* bng = (const float*)d_in[21];
  const float* bnb = (const float*)d_in[22];
  const float* e1W = (const float*)d_in[23];
  const float* e1b = (const float*)d_in[24];
  const float* e2W = (const float*)d_in[25];
  const float* e2b = (const float*)d_in[26];
  float* out = (float*)d_out;

  char* base = (char*)d_ws;
  size_t off = 0;
  auto alloc = [&](size_t bytes)->char*{
    char* r = base + off;
    off = (off + bytes + 255) & ~(size_t)255;
    return r;
  };
  const size_t SZ12 = 64UL*32*12*716*2;
  const size_t SZ13 = 64UL*32*13*716*2;
  bfu*   t1    = (bfu*)  alloc(SZ12);
  bfu*   t2    = (bfu*)  alloc(SZ12);
  bfu*   adjb  = (bfu*)  alloc(64UL*NSQ*2);
  bfu*   P     = (bfu*)  alloc(SZ13);
  bfu*   Q     = (bfu*)  alloc(SZ12);
  bfu*   skipP = (bfu*)  alloc(64UL*416*716*2);
  float* adjp  = (float*)alloc((size_t)NSQ*4);
  float* tmp1  = (float*)alloc(64UL*1600*4);
  float* tmp2  = (float*)alloc(64UL*716*40*4);
  float* p3t   = (float*)alloc(40UL*716*4);
  bfu*   e1Wb  = (bfu*)  alloc(512UL*416*2);
  float* xs    = (float*)alloc(716UL*13*4);
  float* yv    = (float*)alloc(716UL*4);
  float* score = (float*)alloc(716UL*4);
  float* bnred = (float*)alloc(32UL*64*2*4);
  float* bnp   = (float*)alloc(64UL*4);
  float* bnpid = (float*)alloc(64UL*4);
  float* uvec  = (float*)alloc(100UL*4);
  float* ApkT  = (float*)alloc(100UL*100*4);
  int*   ind   = (int*)  alloc(64UL*4);
  int*   mask  = (int*)  alloc(716UL*4);
  int*   idxk  = (int*)  alloc(100UL*4);
  int*   rankv = (int*)  alloc(716UL*4);
  bfu* skipT  = adjb;        // adjb dead after last z-GEMM; 62.6MB >= 38.1MB
  bfu* hidden = t1;          // t1+t2 (67MB) >= 46.9MB

  // dynamic adjacency
  k_ind<<<1,64,0,stream>>>(hist, ind);
  k_dg1<<<64,256,0,stream>>>(p1, pk, ind, tmp1);
  k_dg2<<<dim3(112,64),256,0,stream>>>(p2, tmp1, tmp2);
  k_p3t<<<3,256,0,stream>>>(p3, p3t);
  k_adjrow8<<<dim3(90,64),256,0,stream>>>(p3t, tmp2, adjb);
  // pivotal adjacency (compact structure)
  k_xs<<<716,64,0,stream>>>(hist, saW, sab, xs, yv);
  k_adjp<<<dim3(3,716),256,0,stream>>>(xs, yv, piv, adjp);
  k_score<<<716,256,0,stream>>>(adjp, score);
  k_topk<<<1,256,0,stream>>>(score, mask);
  k_pivprep<<<1,256,0,stream>>>(adjp, mask, idxk, rankv, uvec, ApkT);
  // start conv + weight conversion + identity BN
  k_init_x<<<dim3(3,13,64),256,0,stream>>>(hist, sW, sb, P);
  k_e1perm<<<(512*416+255)/256,256,0,stream>>>(e1W, e1Wb);
  k_bnid<<<1,64,0,stream>>>(bnpid);

  int T = 13;
  bfu* x = P;
  bfu* F = Q;
  static const int off2_[8] = {0,96,176,248,304,352,384,408};
  for (int i = 0; i < 8; ++i){
    int d = (i & 1) ? 2 : 1;
    int Tp = T - d;
    const float* bnin = (i == 0) ? bnpid : bnp;
    dim3 g3(3, Tp, 64);
    dim3 g3v(2, Tp, 64);
    k_fg<<<g3,256,0,stream>>>(x, fW, fb, gW, gb, bnin, F, i, T, Tp, d);
    // xg path: z1 = A*fg, z2 = A*z1, then G over F
    int M1 = 32*Tp; long sx1 = (long)M1*NN;
    dim3 g1(6, (M1+127)/128, 64);
    gemm_mfma<<<g1,256,0,stream>>>(F, adjb, t1, M1, 716, sx1, (long)NSQ, sx1, nullptr, 0, 1, 1);
    gemm_mfma<<<g1,256,0,stream>>>(t1, adjb, t2, M1, 716, sx1, (long)NSQ, sx1, nullptr, 0, 1, 1);
    k_xgmix2<<<g3v,256,0,stream>>>(F, t1, t2, gcW + i*3072, gcb + i*32, alpha, Tp);
    // pgcn path via topk structure: y1 = D(bn(x)) -> t1, y2 = D(y1) -> t2
    int M2 = 64*32*Tp;
    k_pgdiff<<<(M2+3)/4,256,0,stream>>>(x, t1, idxk, rankv, uvec, ApkT, bnin, M2, T, Tp);
    k_pgdiff<<<(M2+3)/4,256,0,stream>>>(t1, t2, idxk, rankv, uvec, ApkT, nullptr, M2, Tp, Tp);
    // combine + residual + skip (coalesced layout)
    k_combine3v<<<g3v,256,0,stream>>>(x, F, t1, t2, pgW + i*3072, pgb + i*32,
        skW + i*256, skb + i*8, alpha, bnin, skipP, T, Tp, d, off2_[i]);
    // batchnorm stats only (apply folded into next layer's loads)
    k_bn1<<<dim3(64,32),256,0,stream>>>(F, bnred, Tp);
    k_bn2<<<32,64,0,stream>>>(bnred, bng, bnb, bnp, i, Tp);
    bfu* tmp = x; x = F; F = tmp;
    T = Tp;
  }
  // end MLP
  k_sktr<<<dim3(12,7,64),256,0,stream>>>(skipP, skipT);
  gemm_mfma<<<dim3(6,4,64),256,0,stream>>>(e1Wb, skipT, hidden, 512, 416,
      0L, 416L*716, 512L*716, e1b, 1, 1, 1);
  k_end2<<<dim3(3,64),256,0,stream>>>(hidden, e2W, e2b, out);
}